// Round 10
// baseline (199.141 us; speedup 1.0000x reference)
//
#include <hip/hip_runtime.h>
#include <hip/hip_bf16.h>

// NPairLoss on MI355X (gfx950).
// loss = mean_i [ log( rowsum_i + e ) - pos_sim_i ] + 0.02*||examples||_F
// rowsum_i = sum_j exp(sim_ij), sim = (A/|A|)·(P/|P|)^T ; diag-replacement -> +e.
//
// R10: fp8-e4m3 scale-MFMA (identity scales 0x7F, exact 3x), 128x128 tile,
// EIGHT waves (4M x 2N; acc[2][4]) -> 2 blocks/CU x 8 waves = 4 waves/SIMD
// (R9 had 2/SIMD and 75% stall cycles). LDS dbuf 2 x 32 KiB = 64 KiB.
//
// Bank-conflict fix (R9: 4.2M cycles, 8-way): 128-B rows alias all rows to
// the same banks (row stride = 0 mod bank period), so slot-XOR-by-row can't
// work. New layout  LDS[phi(r,g)] = G[r][g],  phi(r,g) = r*128 + ((g+r)&7)*16:
// - read octet (consecutive r, fixed g): slot (g+r)&7 distinct -> all 8
//   bank-groups, conflict-free.
// - staging stays coalesced: window lane l -> r = W*8 + (l>>3),
//   g = ((l&7)-(l>>3))&7; each octet covers one row's full 128 B (rotated).

#define NR 8192
#define DD 512
#define E_CONST 2.71828182845904523536f

typedef __attribute__((ext_vector_type(4))) float f32x4_t;
typedef __attribute__((ext_vector_type(4))) int   i32x4_t;
typedef __attribute__((ext_vector_type(8))) int   i32x8_t;
typedef unsigned char uchar;
typedef unsigned int  uint;
#define AS1 __attribute__((address_space(1)))
#define AS3 __attribute__((address_space(3)))

// ---------------- prep: normalize rows -> fp8 e4m3, pos_sim, norm2, zero ----
__global__ __launch_bounds__(128) void prep_kernel(
    const float* __restrict__ ex,
    uchar* __restrict__ Ah, uchar* __restrict__ Ph,
    float* __restrict__ pos_sim, float* __restrict__ norm2,
    float* __restrict__ rowsum)
{
    const int i = blockIdx.x;
    const int t = threadIdx.x;            // 0..127, 4 floats each
    const float4 a = ((const float4*)(ex + (size_t)i * 1024))[t];
    const float4 p = ((const float4*)(ex + (size_t)i * 1024 + 512))[t];
    float sa  = a.x*a.x + a.y*a.y + a.z*a.z + a.w*a.w;
    float sp  = p.x*p.x + p.y*p.y + p.z*p.z + p.w*p.w;
    float sap = a.x*p.x + a.y*p.y + a.z*p.z + a.w*p.w;
    #pragma unroll
    for (int m = 1; m < 64; m <<= 1) {
        sa  += __shfl_xor(sa,  m, 64);
        sp  += __shfl_xor(sp,  m, 64);
        sap += __shfl_xor(sap, m, 64);
    }
    __shared__ float red[3][2];
    if ((t & 63) == 0) { red[0][t>>6] = sa; red[1][t>>6] = sp; red[2][t>>6] = sap; }
    __syncthreads();
    sa  = red[0][0] + red[0][1];
    sp  = red[1][0] + red[1][1];
    sap = red[2][0] + red[2][1];
    const float inva = rsqrtf(sa);
    const float invp = rsqrtf(sp);
    uint pa = 0, pp = 0;
    pa = __builtin_amdgcn_cvt_pk_fp8_f32(a.x * inva, a.y * inva, pa, false);
    pa = __builtin_amdgcn_cvt_pk_fp8_f32(a.z * inva, a.w * inva, pa, true);
    pp = __builtin_amdgcn_cvt_pk_fp8_f32(p.x * invp, p.y * invp, pp, false);
    pp = __builtin_amdgcn_cvt_pk_fp8_f32(p.z * invp, p.w * invp, pp, true);
    ((uint*)Ah)[i * 128 + t] = pa;
    ((uint*)Ph)[i * 128 + t] = pp;
    if (t == 0) {
        pos_sim[i] = sap * inva * invp;
        norm2[i]   = sa + sp;
        rowsum[i]  = 0.0f;
    }
}

// ---------------- GEMM 128^2 fp8, 8 waves, 4 K-slices, 2-phase dbuf ----------
__global__ __launch_bounds__(512, 2) void gemm_kernel(
    const uchar* __restrict__ Ah, const uchar* __restrict__ Ph,
    float* __restrict__ rowsum)
{
    // ls: 2 buffers x (A: 128x128B + B: 128x128B) = 2 x 32 KiB = 64 KiB
    __shared__ uchar ls[65536];
    const int t  = threadIdx.x;           // 0..511
    const int w  = t >> 6;                // wave 0..7
    const int l  = t & 63;
    const int wr = w >> 1, wc = w & 1;    // 4M x 2N wave grid (32-row x 64-col)
    const int ll = l & 15, lh = l >> 4;
    const int m0 = blockIdx.y * 128;
    const int n0 = blockIdx.x * 128;

    f32x4_t acc[2][4];
    #pragma unroll
    for (int i = 0; i < 2; i++)
        #pragma unroll
        for (int j = 0; j < 4; j++)
            acc[i][j] = (f32x4_t){0.f, 0.f, 0.f, 0.f};

    // staging: chunk = one matrix x one slice = 128 rows x 128 B = 16 KiB.
    // 8 waves x 2 windows of 1024 B. Window W: rows W*8..W*8+7.
    // lane l -> r = W*8 + (l>>3), g = ((l&7) - (l>>3)) & 7  (phi involution).
    auto stage = [&](const uchar* src, int s, int matOff, int rowBase) {
        const int buf = s & 1;
        #pragma unroll
        for (int jj = 0; jj < 2; ++jj) {
            const int r = w * 16 + jj * 8 + (l >> 3);
            const int g = ((l & 7) - (l >> 3)) & 7;
            const uchar* gp = src + (size_t)(rowBase + r) * DD + s * 128 + g * 16;
            __builtin_amdgcn_global_load_lds(
                (const AS1 void*)gp,
                (AS3 void*)(&ls[buf * 32768 + matOff + w * 2048 + jj * 1024 + l * 16]),
                16, 0, 0);
        }
    };

    // fragment read: G[R][g] at LDS  R*128 + ((g+R)&7)*16.
    auto rdfrag = [&](int base, int R) -> i32x8_t {
        const int rb = base + R * 128;
        i32x4_t lo = *(const i32x4_t*)&ls[rb + (((lh * 2)     + R) & 7) * 16];
        i32x4_t hi = *(const i32x4_t*)&ls[rb + (((lh * 2) + 1 + R) & 7) * 16];
        return __builtin_shufflevector(lo, hi, 0, 1, 2, 3, 4, 5, 6, 7);
    };

    // prologue: stage slice 0, drain, barrier.
    stage(Ah, 0, 0,     m0);
    stage(Ph, 0, 16384, n0);
    __syncthreads();

    #pragma unroll
    for (int s = 0; s < 4; ++s) {
        // issue next slice's stages EARLY (latency hides under compute)
        if (s < 3) {
            stage(Ah, s + 1, 0,     m0);
            stage(Ph, s + 1, 16384, n0);
        }
        const int aB = (s & 1) * 32768;
        const int bB = aB + 16384;

        i32x8_t bf[4], af[2];
        #pragma unroll
        for (int ni = 0; ni < 4; ++ni)
            bf[ni] = rdfrag(bB, wc * 64 + ni * 16 + ll);
        #pragma unroll
        for (int mi = 0; mi < 2; ++mi)
            af[mi] = rdfrag(aB, wr * 32 + mi * 16 + ll);

        __builtin_amdgcn_s_setprio(1);
        #pragma unroll
        for (int mi = 0; mi < 2; ++mi)
            #pragma unroll
            for (int ni = 0; ni < 4; ++ni)
                acc[mi][ni] =
                    __builtin_amdgcn_mfma_scale_f32_16x16x128_f8f6f4(
                        af[mi], bf[ni], acc[mi][ni],
                        0, 0,                      // cbsz=fp8, blgp=fp8
                        0, 0x7F7F7F7F,             // scale A = 2^0
                        0, 0x7F7F7F7F);            // scale B = 2^0
        __builtin_amdgcn_s_setprio(0);
        __syncthreads();   // drains vmcnt+lgkm: next slice resident, WAR safe
    }

    // epilogue: per-row sum of exp over this block's 128 cols -> atomicAdd.
    // C/D (shape-determined): col = n0 + wc*64 + ni*16 + ll ;
    //                         row = m0 + wr*32 + mi*16 + lh*4 + r
    #pragma unroll
    for (int mi = 0; mi < 2; ++mi) {
        #pragma unroll
        for (int r = 0; r < 4; ++r) {
            float s = __expf(acc[mi][0][r]) + __expf(acc[mi][1][r]) +
                      __expf(acc[mi][2][r]) + __expf(acc[mi][3][r]);
            s += __shfl_xor(s, 1, 64);
            s += __shfl_xor(s, 2, 64);
            s += __shfl_xor(s, 4, 64);
            s += __shfl_xor(s, 8, 64);
            if (ll == 0)
                atomicAdd(&rowsum[m0 + wr * 32 + mi * 16 + lh * 4 + r], s);
        }
    }
}

// ---------------- final reduce (single block, fused) -------------------------
__global__ __launch_bounds__(1024) void final_kernel(
    const float* __restrict__ rowsum, const float* __restrict__ pos_sim,
    const float* __restrict__ norm2, float* __restrict__ out)
{
    const int t = threadIdx.x;
    float s1 = 0.f, s2 = 0.f;
    #pragma unroll
    for (int k = 0; k < NR / 1024; ++k) {
        const int i = k * 1024 + t;
        s1 += logf(rowsum[i] + E_CONST) - pos_sim[i];
        s2 += norm2[i];
    }
    #pragma unroll
    for (int m = 1; m < 64; m <<= 1) {
        s1 += __shfl_xor(s1, m, 64);
        s2 += __shfl_xor(s2, m, 64);
    }
    __shared__ float r1[16], r2[16];
    if ((t & 63) == 0) { r1[t >> 6] = s1; r2[t >> 6] = s2; }
    __syncthreads();
    if (t == 0) {
        float a = 0.f, b = 0.f;
        #pragma unroll
        for (int k = 0; k < 16; ++k) { a += r1[k]; b += r2[k]; }
        out[0] = a * (1.0f / NR) + 0.02f * sqrtf(b);
    }
}

extern "C" void kernel_launch(void* const* d_in, const int* in_sizes, int n_in,
                              void* d_out, int out_size, void* d_ws, size_t ws_size,
                              hipStream_t stream) {
    const float* ex = (const float*)d_in[0];
    float* out = (float*)d_out;
    char* ws = (char*)d_ws;
    uchar* Ah      = (uchar*)(ws);                          // 4 MiB
    uchar* Ph      = (uchar*)(ws + 4194304);                // 4 MiB
    float* possim  = (float*)(ws + 8388608);                // 32 KiB
    float* norm2   = (float*)(ws + 8388608 + 32768);        // 32 KiB
    float* rowsum  = (float*)(ws + 8388608 + 65536);        // 32 KiB

    prep_kernel<<<NR, 128, 0, stream>>>(ex, Ah, Ph, possim, norm2, rowsum);
    gemm_kernel<<<dim3(NR / 128, NR / 128), 512, 0, stream>>>(Ah, Ph, rowsum);
    final_kernel<<<1, 1024, 0, stream>>>(rowsum, possim, norm2, out);
}